// Round 2
// baseline (1534.185 us; speedup 1.0000x reference)
//
#include <hip/hip_runtime.h>
#include <cstdint>
#include <cstddef>

// Problem constants (match reference)
static constexpr int cNA = 100000, cNP = 200000, cNU = 5000;
static constexpr int cDA = 128, cDP = 128, cDU = 64, cH = 32;
static constexpr int cEW = 2000000, cEP = 200000;

// Bucketing for the 2M-edge writes relation:
//  paper side: 128 papers/bucket  -> 1563 buckets
//  author side: 64 authors/bucket -> 1563 buckets
// Each bucket has 8 sub-bins (sub = blockIdx&7) so that, under the default
// round-robin block->XCD mapping, each (bucket,sub) bin region is written by
// one XCD only (no cross-XCD cache-line bouncing).
static constexpr int cPSH = 7, cASH = 6;
static constexpr int cNBP = (cNP + (1 << cPSH) - 1) >> cPSH;  // 1563
static constexpr int cNBA = (cNA + (1 << cASH) - 1) >> cASH;  // 1563

// ---------------------------------------------------------------------------
// prep: build combined per-node-type weight matrices and bias vectors.
//  W_A [128][33] : cols 0..31 = wr_Ws, col 32 = rw_Wd @ rw_ad
//  W_P [128][66] : cols 0..31 = pi_Ws, 32..63 = rw_Ws, 64 = wr_Wd@wr_ad, 65 = rp_Wd@rp_ad
//  W_U [ 64][33] : cols 0..31 = rp_Ws, col 32 = pi_Wd @ pi_ad
//  bias[0..31]=rw_b, bias[32..63]=0.5*(wr_b+rp_b), bias[64..95]=pi_b
// ---------------------------------------------------------------------------
__global__ void prep_kernel(
    const float* __restrict__ wr_Ws, const float* __restrict__ wr_Wd,
    const float* __restrict__ wr_ad, const float* __restrict__ wr_b,
    const float* __restrict__ pi_Ws, const float* __restrict__ pi_Wd,
    const float* __restrict__ pi_ad, const float* __restrict__ pi_b,
    const float* __restrict__ rw_Ws, const float* __restrict__ rw_Wd,
    const float* __restrict__ rw_ad, const float* __restrict__ rw_b,
    const float* __restrict__ rp_Ws, const float* __restrict__ rp_Wd,
    const float* __restrict__ rp_ad, const float* __restrict__ rp_b,
    float* __restrict__ W_A, float* __restrict__ W_P, float* __restrict__ W_U,
    float* __restrict__ bias)
{
    int k = threadIdx.x;  // 128 threads, 1 block
    if (k < 128) {
        for (int c = 0; c < 32; ++c) W_A[k * 33 + c] = wr_Ws[k * 32 + c];
        float dv = 0.f;
        for (int j = 0; j < 32; ++j) dv += rw_Wd[k * 32 + j] * rw_ad[j];
        W_A[k * 33 + 32] = dv;

        for (int c = 0; c < 32; ++c) W_P[k * 66 + c] = pi_Ws[k * 32 + c];
        for (int c = 0; c < 32; ++c) W_P[k * 66 + 32 + c] = rw_Ws[k * 32 + c];
        float d1 = 0.f, d2 = 0.f;
        for (int j = 0; j < 32; ++j) {
            d1 += wr_Wd[k * 32 + j] * wr_ad[j];
            d2 += rp_Wd[k * 32 + j] * rp_ad[j];
        }
        W_P[k * 66 + 64] = d1;
        W_P[k * 66 + 65] = d2;
    }
    if (k < 64) {
        for (int c = 0; c < 32; ++c) W_U[k * 33 + c] = rp_Ws[k * 32 + c];
        float dv = 0.f;
        for (int j = 0; j < 32; ++j) dv += pi_Wd[k * 32 + j] * pi_ad[j];
        W_U[k * 33 + 32] = dv;
    }
    if (k < 32) {
        bias[k]      = rw_b[k];
        bias[32 + k] = 0.5f * (wr_b[k] + rp_b[k]);
        bias[64 + k] = pi_b[k];
    }
}

// ---------------------------------------------------------------------------
// proj: per node type, one pass over x computing hs blocks (+ their s scalars)
// and d scalar columns. One thread per node; W loads are wave-uniform (SGPR).
// ---------------------------------------------------------------------------
template <int D, int NHS, int ND>
__global__ __launch_bounds__(256) void proj_kernel(
    const float* __restrict__ x, const float* __restrict__ W, int N,
    const float* __restrict__ as0, const float* __restrict__ as1,
    float* __restrict__ hs0, float* __restrict__ s0,
    float* __restrict__ hs1, float* __restrict__ s1,
    float* __restrict__ dd0, float* __restrict__ dd1)
{
    constexpr int C = NHS * 32 + ND;
    int n = blockIdx.x * blockDim.x + threadIdx.x;
    if (n >= N) return;
    float acc[C];
#pragma unroll
    for (int c = 0; c < C; ++c) acc[c] = 0.f;
    const float* xr = x + (size_t)n * D;
    for (int k = 0; k < D; k += 4) {
        float4 xv = *reinterpret_cast<const float4*>(xr + k);
        const float* w = W + (size_t)k * C;
#pragma unroll
        for (int c = 0; c < C; ++c) acc[c] += xv.x * w[c];
#pragma unroll
        for (int c = 0; c < C; ++c) acc[c] += xv.y * w[C + c];
#pragma unroll
        for (int c = 0; c < C; ++c) acc[c] += xv.z * w[2 * C + c];
#pragma unroll
        for (int c = 0; c < C; ++c) acc[c] += xv.w * w[3 * C + c];
    }
    {
        float sv = 0.f;
#pragma unroll
        for (int c = 0; c < 32; ++c) sv += acc[c] * as0[c];
        s0[n] = sv;
        float4* o = reinterpret_cast<float4*>(hs0 + (size_t)n * 32);
#pragma unroll
        for (int i = 0; i < 8; ++i)
            o[i] = make_float4(acc[4 * i], acc[4 * i + 1], acc[4 * i + 2], acc[4 * i + 3]);
    }
    if constexpr (NHS == 2) {
        float sv = 0.f;
#pragma unroll
        for (int c = 0; c < 32; ++c) sv += acc[32 + c] * as1[c];
        s1[n] = sv;
        float4* o = reinterpret_cast<float4*>(hs1 + (size_t)n * 32);
#pragma unroll
        for (int i = 0; i < 8; ++i)
            o[i] = make_float4(acc[32 + 4 * i], acc[32 + 4 * i + 1],
                               acc[32 + 4 * i + 2], acc[32 + 4 * i + 3]);
    }
    dd0[n] = acc[NHS * 32];
    if constexpr (ND == 2) dd1[n] = acc[NHS * 32 + 1];
}

// ---------------------------------------------------------------------------
// bucket hist: count edges per (bucket, sub) for both directions.
// sub = blockIdx&7 must match bbin_kernel's mapping (same grid geometry).
// ---------------------------------------------------------------------------
__global__ __launch_bounds__(256) void bhist_kernel(
    const int* __restrict__ wsrc, const int* __restrict__ wdst,
    int* __restrict__ cntP8, int* __restrict__ cntA8, int E)
{
    int i = blockIdx.x * 256 + threadIdx.x;
    if (i >= E) return;
    int sub = blockIdx.x & 7;
    atomicAdd(&cntP8[(wdst[i] >> cPSH) * 8 + sub], 1);
    atomicAdd(&cntA8[(wsrc[i] >> cASH) * 8 + sub], 1);
}

// Two-level exclusive scan: A) per-block (2048-elem chunk) sums,
// B) serial scan over block sums (small), C) in-block scan + offset.
__global__ __launch_bounds__(256) void scanA_kernel(
    const int* __restrict__ cnt, int* __restrict__ bsum, int n)
{
    int t = threadIdx.x;
    int i0 = blockIdx.x * 2048 + t * 8;
    int s = 0;
#pragma unroll
    for (int j = 0; j < 8; ++j) {
        int i = i0 + j;
        s += (i < n) ? cnt[i] : 0;
    }
    for (int off = 1; off < 64; off <<= 1) s += __shfl_xor(s, off);
    __shared__ int ws_[4];
    int lane = t & 63, w = t >> 6;
    if (lane == 0) ws_[w] = s;
    __syncthreads();
    if (t == 0) bsum[blockIdx.x] = ws_[0] + ws_[1] + ws_[2] + ws_[3];
}

__global__ void scanB_kernel(int* __restrict__ bsum, int nb)
{
    // 1 thread; nb is small
    int run = 0;
    for (int i = 0; i < nb; ++i) { int v = bsum[i]; bsum[i] = run; run += v; }
}

__global__ __launch_bounds__(256) void scanC_kernel(
    const int* __restrict__ cnt, const int* __restrict__ bsum,
    int* __restrict__ rowstart, int* __restrict__ cursor, int n)
{
    int t = threadIdx.x;
    int i0 = blockIdx.x * 2048 + t * 8;
    int vals[8];
    int s = 0;
#pragma unroll
    for (int j = 0; j < 8; ++j) {
        int i = i0 + j;
        vals[j] = (i < n) ? cnt[i] : 0;
        s += vals[j];
    }
    int lane = t & 63, w = t >> 6;
    int incl = s;
    for (int off = 1; off < 64; off <<= 1) {
        int u = __shfl_up(incl, off);
        if (lane >= off) incl += u;
    }
    __shared__ int wsum[4];
    if (lane == 63) wsum[w] = incl;
    __syncthreads();
    int woff = 0;
    for (int k = 0; k < w; ++k) woff += wsum[k];
    int excl = incl - s + woff + bsum[blockIdx.x];
#pragma unroll
    for (int j = 0; j < 8; ++j) {
        int i = i0 + j;
        if (i < n) { rowstart[i] = excl; cursor[i] = excl; }
        excl += vals[j];
    }
}

// ---------------------------------------------------------------------------
// bin: place a packed (src<<shift | dst_low) word per edge into its
// (bucket, sub) region. Writes are sequential within each region; with the
// round-robin block->XCD mapping each region is written by one XCD.
// ---------------------------------------------------------------------------
__global__ __launch_bounds__(256) void bbin_kernel(
    const int* __restrict__ wsrc, const int* __restrict__ wdst,
    int* __restrict__ curP8, int* __restrict__ curA8,
    int* __restrict__ binW, int* __restrict__ binR, int E)
{
    int i = blockIdx.x * 256 + threadIdx.x;
    if (i >= E) return;
    int sub = blockIdx.x & 7;
    int s = wsrc[i], d = wdst[i];
    int p = atomicAdd(&curP8[(d >> cPSH) * 8 + sub], 1);
    binW[p] = (s << cPSH) | (d & ((1 << cPSH) - 1));
    int q = atomicAdd(&curA8[(s >> cASH) * 8 + sub], 1);
    binR[q] = (d << cASH) | (s & ((1 << cASH) - 1));
}

// ---------------------------------------------------------------------------
// bucket accumulate: one block per dst-bucket. Accumulator (BN nodes x 32ch)
// and denominator live in LDS; 32-lane group per edge; LDS atomicAdd is
// conflict-free (bank = lane). Single coalesced global write per bucket.
// ---------------------------------------------------------------------------
template <int BSHIFT>
__global__ __launch_bounds__(256) void bucket_acc_kernel(
    const int* __restrict__ binv, const int* __restrict__ start,
    const float* __restrict__ sval, const float* __restrict__ dval,
    const float* __restrict__ hs,
    float* __restrict__ acc, float* __restrict__ den, int N, int E)
{
    constexpr int BN = 1 << BSHIFT;
    __shared__ float accL[BN * 32];
    __shared__ float denL[BN];
    int b = blockIdx.x;
    int b0 = b << BSHIFT;
    int t = threadIdx.x;
    for (int i = t; i < BN * 32; i += 256) accL[i] = 0.f;
    for (int i = t; i < BN; i += 256) denL[i] = 0.f;
    __syncthreads();
    int begin = start[b * 8];
    int end = (b == (int)gridDim.x - 1) ? E : start[(b + 1) * 8];
    int g = t >> 5, lane = t & 31;
    for (int i = begin + g; i < end; i += 8) {
        int v = binv[i];
        int dl = v & (BN - 1);
        int s = v >> BSHIFT;
        float ev = sval[s] + dval[b0 + dl];
        ev = ev >= 0.f ? ev : 0.2f * ev;
        float ex = __expf(ev);
        if (lane == 0) atomicAdd(&denL[dl], ex);
        atomicAdd(&accL[dl * 32 + lane], ex * hs[(size_t)s * 32 + lane]);
    }
    __syncthreads();
    int nOut = N - b0;
    if (nOut > BN) nOut = BN;
    for (int i = t; i < nOut * 32; i += 256)
        acc[(size_t)b0 * 32 + i] = accL[i];
    for (int i = t; i < nOut; i += 256)
        den[b0 + i] = denL[i];
}

// ---------------------------------------------------------------------------
// edge: atomic path, kept only for the small pub relations (200K edges).
// ---------------------------------------------------------------------------
__global__ __launch_bounds__(256) void edge_kernel(
    const int* __restrict__ src, const int* __restrict__ dst,
    const float* __restrict__ s, const float* __restrict__ d,
    const float* __restrict__ hs, float* __restrict__ den,
    float* __restrict__ acc, int E)
{
    int g = blockIdx.x * blockDim.x + threadIdx.x;
    int e = g >> 5;
    if (e >= E) return;
    int h = g & 31;
    int si = src[e], di = dst[e];
    float ev = s[si] + d[di];
    ev = ev >= 0.f ? ev : 0.2f * ev;
    float ex = __expf(ev);
    if (h == 0) atomicAdd(den + di, ex);
    atomicAdd(acc + (size_t)di * 32 + h, ex * hs[(size_t)si * 32 + h]);
}

// ---------------------------------------------------------------------------
// final: combine relations, /den (0 if no in-edges), +bias, relu, @lin_W+lin_b
// ---------------------------------------------------------------------------
__global__ __launch_bounds__(256) void final_kernel(
    const float* __restrict__ acc0, const float* __restrict__ den0,
    const float* __restrict__ acc1, const float* __restrict__ den1,
    const float* __restrict__ bias, float scale,
    const float* __restrict__ linW, const float* __restrict__ linb,
    float* __restrict__ out, int N)
{
    int n = blockIdx.x * blockDim.x + threadIdx.x;
    if (n >= N) return;
    float v[32];
    {
        float dn = den0[n];
        float inv = dn > 0.f ? 1.f / dn : 0.f;
        const float4* a0 = reinterpret_cast<const float4*>(acc0 + (size_t)n * 32);
#pragma unroll
        for (int i = 0; i < 8; ++i) {
            float4 t = a0[i];
            v[4 * i] = t.x * inv; v[4 * i + 1] = t.y * inv;
            v[4 * i + 2] = t.z * inv; v[4 * i + 3] = t.w * inv;
        }
    }
    if (acc1 != nullptr) {
        float dn = den1[n];
        float inv = dn > 0.f ? 1.f / dn : 0.f;
        const float4* a1 = reinterpret_cast<const float4*>(acc1 + (size_t)n * 32);
#pragma unroll
        for (int i = 0; i < 8; ++i) {
            float4 t = a1[i];
            v[4 * i] += t.x * inv; v[4 * i + 1] += t.y * inv;
            v[4 * i + 2] += t.z * inv; v[4 * i + 3] += t.w * inv;
        }
    }
#pragma unroll
    for (int h = 0; h < 32; ++h) {
        float t = scale * v[h] + bias[h];
        v[h] = t > 0.f ? t : 0.f;
    }
    float y[32];
#pragma unroll
    for (int j = 0; j < 32; ++j) y[j] = linb[j];
#pragma unroll
    for (int h = 0; h < 32; ++h) {
        float vh = v[h];
#pragma unroll
        for (int j = 0; j < 32; ++j) y[j] += vh * linW[h * 32 + j];
    }
    float4* o = reinterpret_cast<float4*>(out + (size_t)n * 32);
#pragma unroll
    for (int i = 0; i < 8; ++i)
        o[i] = make_float4(y[4 * i], y[4 * i + 1], y[4 * i + 2], y[4 * i + 3]);
}

extern "C" void kernel_launch(void* const* d_in, const int* in_sizes, int n_in,
                              void* d_out, int out_size, void* d_ws, size_t ws_size,
                              hipStream_t stream)
{
    const float* x_author = (const float*)d_in[0];
    const float* x_paper  = (const float*)d_in[1];
    const float* x_unit   = (const float*)d_in[2];
    const int* writes_src = (const int*)d_in[3];
    const int* writes_dst = (const int*)d_in[4];
    const int* pub_src    = (const int*)d_in[5];
    const int* pub_dst    = (const int*)d_in[6];
    const float* wr_Ws = (const float*)d_in[7];
    const float* wr_Wd = (const float*)d_in[8];
    const float* wr_as = (const float*)d_in[9];
    const float* wr_ad = (const float*)d_in[10];
    const float* wr_b  = (const float*)d_in[11];
    const float* pi_Ws = (const float*)d_in[12];
    const float* pi_Wd = (const float*)d_in[13];
    const float* pi_as = (const float*)d_in[14];
    const float* pi_ad = (const float*)d_in[15];
    const float* pi_b  = (const float*)d_in[16];
    const float* rw_Ws = (const float*)d_in[17];
    const float* rw_Wd = (const float*)d_in[18];
    const float* rw_as = (const float*)d_in[19];
    const float* rw_ad = (const float*)d_in[20];
    const float* rw_b  = (const float*)d_in[21];
    const float* rp_Ws = (const float*)d_in[22];
    const float* rp_Wd = (const float*)d_in[23];
    const float* rp_as = (const float*)d_in[24];
    const float* rp_ad = (const float*)d_in[25];
    const float* rp_b  = (const float*)d_in[26];
    const float* lin_W = (const float*)d_in[27];
    const float* lin_b = (const float*)d_in[28];
    float* out = (float*)d_out;
    float* ws = (float*)d_ws;

    // workspace layout (float offsets, padded to 64)
    size_t off = 0;
    auto A = [&](size_t nf) { size_t o = off; off += (nf + 63) & ~(size_t)63; return o; };
    size_t oWA   = A(128 * 33);
    size_t oWP   = A(128 * 66);
    size_t oWU   = A(64 * 33);
    size_t oBias = A(96);
    size_t oHsWr = A((size_t)cNA * 32);
    size_t oHsPi = A((size_t)cNP * 32);
    size_t oHsRw = A((size_t)cNP * 32);
    size_t oHsRp = A((size_t)cNU * 32);
    size_t oSwr  = A(cNA);
    size_t oSpi  = A(cNP);
    size_t oSrw  = A(cNP);
    size_t oSrp  = A(cNU);
    size_t oDwr  = A(cNP);
    size_t oDrp  = A(cNP);
    size_t oDpi  = A(cNU);
    size_t oDrw  = A(cNA);
    // bucket-path buffers (written each launch; no zeroing needed)
    size_t oAccWr = A((size_t)cNP * 32);
    size_t oDenWr = A(cNP);
    size_t oAccRw = A((size_t)cNA * 32);
    size_t oDenRw = A(cNA);
    size_t oStP8  = A((size_t)cNBP * 8);
    size_t oCurP8 = A((size_t)cNBP * 8);
    size_t oStA8  = A((size_t)cNBA * 8);
    size_t oCurA8 = A((size_t)cNBA * 8);
    size_t oBsP   = A(64);
    size_t oBsA   = A(64);
    size_t oBinW  = A(cEW);   // packed (author<<7 | paper&127), grouped by paper bucket
    size_t oBinR  = A(cEW);   // packed (paper<<6 | author&63), grouped by author bucket
    // zero-region: bucket histograms + atomic-path accumulators (pub relations)
    size_t zs = off;
    size_t oCntP8 = A((size_t)cNBP * 8);
    size_t oCntA8 = A((size_t)cNBA * 8);
    size_t oDenRp = A(cNP);
    size_t oDenPi = A(cNU);
    size_t oAccRp = A((size_t)cNP * 32);
    size_t oAccPi = A((size_t)cNU * 32);
    size_t ze = off;

    hipMemsetAsync((void*)(ws + zs), 0, (ze - zs) * sizeof(float), stream);

    prep_kernel<<<1, 128, 0, stream>>>(
        wr_Ws, wr_Wd, wr_ad, wr_b,
        pi_Ws, pi_Wd, pi_ad, pi_b,
        rw_Ws, rw_Wd, rw_ad, rw_b,
        rp_Ws, rp_Wd, rp_ad, rp_b,
        ws + oWA, ws + oWP, ws + oWU, ws + oBias);

    // ---- bucket-bin build for writes relation (both directions) ----
    {
        int* cntP8 = (int*)(ws + oCntP8);
        int* cntA8 = (int*)(ws + oCntA8);
        int* stP8  = (int*)(ws + oStP8);
        int* curP8 = (int*)(ws + oCurP8);
        int* stA8  = (int*)(ws + oStA8);
        int* curA8 = (int*)(ws + oCurA8);
        int* bsP   = (int*)(ws + oBsP);
        int* bsA   = (int*)(ws + oBsA);
        int* binW  = (int*)(ws + oBinW);
        int* binR  = (int*)(ws + oBinR);

        int eb = (cEW + 255) / 256;
        bhist_kernel<<<eb, 256, 0, stream>>>(writes_src, writes_dst, cntP8, cntA8, cEW);

        int nP8 = cNBP * 8, nA8 = cNBA * 8;
        int nbP = (nP8 + 2047) / 2048;
        int nbA = (nA8 + 2047) / 2048;
        scanA_kernel<<<nbP, 256, 0, stream>>>(cntP8, bsP, nP8);
        scanA_kernel<<<nbA, 256, 0, stream>>>(cntA8, bsA, nA8);
        scanB_kernel<<<1, 1, 0, stream>>>(bsP, nbP);
        scanB_kernel<<<1, 1, 0, stream>>>(bsA, nbA);
        scanC_kernel<<<nbP, 256, 0, stream>>>(cntP8, bsP, stP8, curP8, nP8);
        scanC_kernel<<<nbA, 256, 0, stream>>>(cntA8, bsA, stA8, curA8, nA8);

        bbin_kernel<<<eb, 256, 0, stream>>>(writes_src, writes_dst,
                                            curP8, curA8, binW, binR, cEW);
    }

    proj_kernel<128, 1, 1><<<(cNA + 255) / 256, 256, 0, stream>>>(
        x_author, ws + oWA, cNA, wr_as, nullptr,
        ws + oHsWr, ws + oSwr, nullptr, nullptr, ws + oDrw, nullptr);
    proj_kernel<128, 2, 2><<<(cNP + 255) / 256, 256, 0, stream>>>(
        x_paper, ws + oWP, cNP, pi_as, rw_as,
        ws + oHsPi, ws + oSpi, ws + oHsRw, ws + oSrw, ws + oDwr, ws + oDrp);
    proj_kernel<64, 1, 1><<<(cNU + 255) / 256, 256, 0, stream>>>(
        x_unit, ws + oWU, cNU, rp_as, nullptr,
        ws + oHsRp, ws + oSrp, nullptr, nullptr, ws + oDpi, nullptr);

    // ---- writes relation: LDS bucket accumulation ----
    // wr: author -> paper (buckets of 128 papers; src=author)
    bucket_acc_kernel<cPSH><<<cNBP, 256, 0, stream>>>(
        (int*)(ws + oBinW), (int*)(ws + oStP8),
        ws + oSwr, ws + oDwr, ws + oHsWr,
        ws + oAccWr, ws + oDenWr, cNP, cEW);
    // rw: paper -> author (buckets of 64 authors; src=paper)
    bucket_acc_kernel<cASH><<<cNBA, 256, 0, stream>>>(
        (int*)(ws + oBinR), (int*)(ws + oStA8),
        ws + oSrw, ws + oDrw, ws + oHsRw,
        ws + oAccRw, ws + oDenRw, cNA, cEW);

    // ---- pub relations: atomic path (small: 200K edges) ----
    {
        int blocks = (int)(((long long)cEP * 32 + 255) / 256);
        // pi: paper -> unit (acc region 640KB)
        edge_kernel<<<blocks, 256, 0, stream>>>(
            pub_src, pub_dst, ws + oSpi, ws + oDpi, ws + oHsPi,
            ws + oDenPi, ws + oAccPi, cEP);
        // rp: unit -> paper
        edge_kernel<<<blocks, 256, 0, stream>>>(
            pub_dst, pub_src, ws + oSrp, ws + oDrp, ws + oHsRp,
            ws + oDenRp, ws + oAccRp, cEP);
    }

    // outputs: author, paper, unit (concatenated)
    final_kernel<<<(cNA + 255) / 256, 256, 0, stream>>>(
        ws + oAccRw, ws + oDenRw, nullptr, nullptr,
        ws + oBias + 0, 1.0f, lin_W, lin_b, out, cNA);
    final_kernel<<<(cNP + 255) / 256, 256, 0, stream>>>(
        ws + oAccWr, ws + oDenWr, ws + oAccRp, ws + oDenRp,
        ws + oBias + 32, 0.5f, lin_W, lin_b, out + (size_t)cNA * 32, cNP);
    final_kernel<<<(cNU + 255) / 256, 256, 0, stream>>>(
        ws + oAccPi, ws + oDenPi, nullptr, nullptr,
        ws + oBias + 64, 1.0f, lin_W, lin_b, out + (size_t)(cNA + cNP) * 32, cNU);
}

// Round 3
// 1383.479 us; speedup vs baseline: 1.1089x; 1.1089x over previous
//
#include <hip/hip_runtime.h>
#include <cstdint>
#include <cstddef>

// Problem constants (match reference)
static constexpr int cNA = 100000, cNP = 200000, cNU = 5000;
static constexpr int cDA = 128, cDP = 128, cDU = 64, cH = 32;
static constexpr int cEW = 2000000, cEP = 200000;

// Bucketing for the 2M-edge writes relation:
//  paper side: 64 papers/bucket  -> 3125 buckets
//  author side: 32 authors/bucket -> 3125 buckets
// Each bucket has 8 sub-bins (sub = blockIdx&7) so that, under the default
// round-robin block->XCD mapping, each (bucket,sub) bin region is written by
// one XCD only (no cross-XCD cache-line bouncing).
static constexpr int cPSH = 6, cASH = 5;
static constexpr int cNBP = (cNP + (1 << cPSH) - 1) >> cPSH;  // 3125
static constexpr int cNBA = (cNA + (1 << cASH) - 1) >> cASH;  // 3125

// ---------------------------------------------------------------------------
// prep: build combined per-node-type weight matrices and bias vectors.
//  W_A [128][33] : cols 0..31 = wr_Ws, col 32 = rw_Wd @ rw_ad
//  W_P [128][66] : cols 0..31 = pi_Ws, 32..63 = rw_Ws, 64 = wr_Wd@wr_ad, 65 = rp_Wd@rp_ad
//  W_U [ 64][33] : cols 0..31 = rp_Ws, col 32 = pi_Wd @ pi_ad
//  bias[0..31]=rw_b, bias[32..63]=0.5*(wr_b+rp_b), bias[64..95]=pi_b
// ---------------------------------------------------------------------------
__global__ void prep_kernel(
    const float* __restrict__ wr_Ws, const float* __restrict__ wr_Wd,
    const float* __restrict__ wr_ad, const float* __restrict__ wr_b,
    const float* __restrict__ pi_Ws, const float* __restrict__ pi_Wd,
    const float* __restrict__ pi_ad, const float* __restrict__ pi_b,
    const float* __restrict__ rw_Ws, const float* __restrict__ rw_Wd,
    const float* __restrict__ rw_ad, const float* __restrict__ rw_b,
    const float* __restrict__ rp_Ws, const float* __restrict__ rp_Wd,
    const float* __restrict__ rp_ad, const float* __restrict__ rp_b,
    float* __restrict__ W_A, float* __restrict__ W_P, float* __restrict__ W_U,
    float* __restrict__ bias)
{
    int k = threadIdx.x;  // 128 threads, 1 block
    if (k < 128) {
        for (int c = 0; c < 32; ++c) W_A[k * 33 + c] = wr_Ws[k * 32 + c];
        float dv = 0.f;
        for (int j = 0; j < 32; ++j) dv += rw_Wd[k * 32 + j] * rw_ad[j];
        W_A[k * 33 + 32] = dv;

        for (int c = 0; c < 32; ++c) W_P[k * 66 + c] = pi_Ws[k * 32 + c];
        for (int c = 0; c < 32; ++c) W_P[k * 66 + 32 + c] = rw_Ws[k * 32 + c];
        float d1 = 0.f, d2 = 0.f;
        for (int j = 0; j < 32; ++j) {
            d1 += wr_Wd[k * 32 + j] * wr_ad[j];
            d2 += rp_Wd[k * 32 + j] * rp_ad[j];
        }
        W_P[k * 66 + 64] = d1;
        W_P[k * 66 + 65] = d2;
    }
    if (k < 64) {
        for (int c = 0; c < 32; ++c) W_U[k * 33 + c] = rp_Ws[k * 32 + c];
        float dv = 0.f;
        for (int j = 0; j < 32; ++j) dv += pi_Wd[k * 32 + j] * pi_ad[j];
        W_U[k * 33 + 32] = dv;
    }
    if (k < 32) {
        bias[k]      = rw_b[k];
        bias[32 + k] = 0.5f * (wr_b[k] + rp_b[k]);
        bias[64 + k] = pi_b[k];
    }
}

// ---------------------------------------------------------------------------
// proj: per node type, one pass over x computing hs blocks (+ their s scalars)
// and d scalar columns. One thread per node; W loads are wave-uniform (SGPR).
// ---------------------------------------------------------------------------
template <int D, int NHS, int ND>
__global__ __launch_bounds__(256) void proj_kernel(
    const float* __restrict__ x, const float* __restrict__ W, int N,
    const float* __restrict__ as0, const float* __restrict__ as1,
    float* __restrict__ hs0, float* __restrict__ s0,
    float* __restrict__ hs1, float* __restrict__ s1,
    float* __restrict__ dd0, float* __restrict__ dd1)
{
    constexpr int C = NHS * 32 + ND;
    int n = blockIdx.x * blockDim.x + threadIdx.x;
    if (n >= N) return;
    float acc[C];
#pragma unroll
    for (int c = 0; c < C; ++c) acc[c] = 0.f;
    const float* xr = x + (size_t)n * D;
    for (int k = 0; k < D; k += 4) {
        float4 xv = *reinterpret_cast<const float4*>(xr + k);
        const float* w = W + (size_t)k * C;
#pragma unroll
        for (int c = 0; c < C; ++c) acc[c] += xv.x * w[c];
#pragma unroll
        for (int c = 0; c < C; ++c) acc[c] += xv.y * w[C + c];
#pragma unroll
        for (int c = 0; c < C; ++c) acc[c] += xv.z * w[2 * C + c];
#pragma unroll
        for (int c = 0; c < C; ++c) acc[c] += xv.w * w[3 * C + c];
    }
    {
        float sv = 0.f;
#pragma unroll
        for (int c = 0; c < 32; ++c) sv += acc[c] * as0[c];
        s0[n] = sv;
        float4* o = reinterpret_cast<float4*>(hs0 + (size_t)n * 32);
#pragma unroll
        for (int i = 0; i < 8; ++i)
            o[i] = make_float4(acc[4 * i], acc[4 * i + 1], acc[4 * i + 2], acc[4 * i + 3]);
    }
    if constexpr (NHS == 2) {
        float sv = 0.f;
#pragma unroll
        for (int c = 0; c < 32; ++c) sv += acc[32 + c] * as1[c];
        s1[n] = sv;
        float4* o = reinterpret_cast<float4*>(hs1 + (size_t)n * 32);
#pragma unroll
        for (int i = 0; i < 8; ++i)
            o[i] = make_float4(acc[32 + 4 * i], acc[32 + 4 * i + 1],
                               acc[32 + 4 * i + 2], acc[32 + 4 * i + 3]);
    }
    dd0[n] = acc[NHS * 32];
    if constexpr (ND == 2) dd1[n] = acc[NHS * 32 + 1];
}

// ---------------------------------------------------------------------------
// bucket hist: count edges per (bucket, sub) for both directions.
// sub = blockIdx&7 must match bbin_kernel's mapping (same grid geometry).
// ---------------------------------------------------------------------------
__global__ __launch_bounds__(256) void bhist_kernel(
    const int* __restrict__ wsrc, const int* __restrict__ wdst,
    int* __restrict__ cntP8, int* __restrict__ cntA8, int E)
{
    int i = blockIdx.x * 256 + threadIdx.x;
    if (i >= E) return;
    int sub = blockIdx.x & 7;
    atomicAdd(&cntP8[(wdst[i] >> cPSH) * 8 + sub], 1);
    atomicAdd(&cntA8[(wsrc[i] >> cASH) * 8 + sub], 1);
}

// Two-level exclusive scan: A) per-block (2048-elem chunk) sums,
// B) serial scan over block sums (small), C) in-block scan + offset.
__global__ __launch_bounds__(256) void scanA_kernel(
    const int* __restrict__ cnt, int* __restrict__ bsum, int n)
{
    int t = threadIdx.x;
    int i0 = blockIdx.x * 2048 + t * 8;
    int s = 0;
#pragma unroll
    for (int j = 0; j < 8; ++j) {
        int i = i0 + j;
        s += (i < n) ? cnt[i] : 0;
    }
    for (int off = 1; off < 64; off <<= 1) s += __shfl_xor(s, off);
    __shared__ int ws_[4];
    int lane = t & 63, w = t >> 6;
    if (lane == 0) ws_[w] = s;
    __syncthreads();
    if (t == 0) bsum[blockIdx.x] = ws_[0] + ws_[1] + ws_[2] + ws_[3];
}

__global__ void scanB_kernel(int* __restrict__ bsum, int nb)
{
    // 1 thread; nb is small
    int run = 0;
    for (int i = 0; i < nb; ++i) { int v = bsum[i]; bsum[i] = run; run += v; }
}

__global__ __launch_bounds__(256) void scanC_kernel(
    const int* __restrict__ cnt, const int* __restrict__ bsum,
    int* __restrict__ rowstart, int* __restrict__ cursor, int n)
{
    int t = threadIdx.x;
    int i0 = blockIdx.x * 2048 + t * 8;
    int vals[8];
    int s = 0;
#pragma unroll
    for (int j = 0; j < 8; ++j) {
        int i = i0 + j;
        vals[j] = (i < n) ? cnt[i] : 0;
        s += vals[j];
    }
    int lane = t & 63, w = t >> 6;
    int incl = s;
    for (int off = 1; off < 64; off <<= 1) {
        int u = __shfl_up(incl, off);
        if (lane >= off) incl += u;
    }
    __shared__ int wsum[4];
    if (lane == 63) wsum[w] = incl;
    __syncthreads();
    int woff = 0;
    for (int k = 0; k < w; ++k) woff += wsum[k];
    int excl = incl - s + woff + bsum[blockIdx.x];
#pragma unroll
    for (int j = 0; j < 8; ++j) {
        int i = i0 + j;
        if (i < n) { rowstart[i] = excl; cursor[i] = excl; }
        excl += vals[j];
    }
}

// ---------------------------------------------------------------------------
// bin: place a packed (src<<shift | dst_low) word per edge into its
// (bucket, sub) region. Active cursor lines (~800KB) stay L2-resident, so
// the scattered 4B stores coalesce in L2 before flushing.
// ---------------------------------------------------------------------------
__global__ __launch_bounds__(256) void bbin_kernel(
    const int* __restrict__ wsrc, const int* __restrict__ wdst,
    int* __restrict__ curP8, int* __restrict__ curA8,
    int* __restrict__ binW, int* __restrict__ binR, int E)
{
    int i = blockIdx.x * 256 + threadIdx.x;
    if (i >= E) return;
    int sub = blockIdx.x & 7;
    int s = wsrc[i], d = wdst[i];
    int p = atomicAdd(&curP8[(d >> cPSH) * 8 + sub], 1);
    binW[p] = (s << cPSH) | (d & ((1 << cPSH) - 1));
    int q = atomicAdd(&curA8[(s >> cASH) * 8 + sub], 1);
    binR[q] = (d << cASH) | (s & ((1 << cASH) - 1));
}

// ---------------------------------------------------------------------------
// bucket accumulate: one block per dst-bucket. Accumulator (BN nodes x 32ch),
// denominator, and dval live in LDS; each 32-lane group processes a
// contiguous 4-edge chunk per iteration (all loads issued before any use ->
// 4 overlapping latency chains/group, 32 in-flight edges/block).
// Single coalesced global write per bucket.
// ---------------------------------------------------------------------------
template <int BSHIFT>
__global__ __launch_bounds__(256) void bucket_acc_kernel(
    const int* __restrict__ binv, const int* __restrict__ start,
    const float* __restrict__ sval, const float* __restrict__ dval,
    const float* __restrict__ hs,
    float* __restrict__ acc, float* __restrict__ den, int N, int E)
{
    constexpr int BN = 1 << BSHIFT;
    __shared__ float accL[BN * 32];
    __shared__ float denL[BN];
    __shared__ float dvalL[BN];
    int b = blockIdx.x;
    int b0 = b << BSHIFT;
    int t = threadIdx.x;
    int nOut = N - b0;
    if (nOut > BN) nOut = BN;
    for (int i = t; i < BN * 32; i += 256) accL[i] = 0.f;
    if (t < BN) {
        denL[t] = 0.f;
        dvalL[t] = (t < nOut) ? dval[b0 + t] : 0.f;
    }
    __syncthreads();
    int begin = start[b * 8];
    int end = (b == (int)gridDim.x - 1) ? E : start[(b + 1) * 8];
    int g = t >> 5, lane = t & 31;
    for (int i = begin + g * 4; i < end; i += 32) {
        int m = end - i;
        if (m > 4) m = 4;
        int v[4];
        float sv[4], hh[4], dd[4];
#pragma unroll
        for (int k = 0; k < 4; ++k)
            if (k < m) v[k] = binv[i + k];
#pragma unroll
        for (int k = 0; k < 4; ++k)
            if (k < m) {
                int s = v[k] >> BSHIFT;
                sv[k] = sval[s];
                hh[k] = hs[(size_t)s * 32 + lane];
                dd[k] = dvalL[v[k] & (BN - 1)];
            }
#pragma unroll
        for (int k = 0; k < 4; ++k)
            if (k < m) {
                float ev = sv[k] + dd[k];
                ev = ev >= 0.f ? ev : 0.2f * ev;
                float ex = __expf(ev);
                int dl = v[k] & (BN - 1);
                if (lane == 0) atomicAdd(&denL[dl], ex);
                atomicAdd(&accL[dl * 32 + lane], ex * hh[k]);
            }
    }
    __syncthreads();
    for (int i = t; i < nOut * 32; i += 256)
        acc[(size_t)b0 * 32 + i] = accL[i];
    for (int i = t; i < nOut; i += 256)
        den[b0 + i] = denL[i];
}

// ---------------------------------------------------------------------------
// edge: atomic path, kept only for the small pub relations (200K edges).
// ---------------------------------------------------------------------------
__global__ __launch_bounds__(256) void edge_kernel(
    const int* __restrict__ src, const int* __restrict__ dst,
    const float* __restrict__ s, const float* __restrict__ d,
    const float* __restrict__ hs, float* __restrict__ den,
    float* __restrict__ acc, int E)
{
    int g = blockIdx.x * blockDim.x + threadIdx.x;
    int e = g >> 5;
    if (e >= E) return;
    int h = g & 31;
    int si = src[e], di = dst[e];
    float ev = s[si] + d[di];
    ev = ev >= 0.f ? ev : 0.2f * ev;
    float ex = __expf(ev);
    if (h == 0) atomicAdd(den + di, ex);
    atomicAdd(acc + (size_t)di * 32 + h, ex * hs[(size_t)si * 32 + h]);
}

// ---------------------------------------------------------------------------
// final: combine relations, /den (0 if no in-edges), +bias, relu, @lin_W+lin_b
// ---------------------------------------------------------------------------
__global__ __launch_bounds__(256) void final_kernel(
    const float* __restrict__ acc0, const float* __restrict__ den0,
    const float* __restrict__ acc1, const float* __restrict__ den1,
    const float* __restrict__ bias, float scale,
    const float* __restrict__ linW, const float* __restrict__ linb,
    float* __restrict__ out, int N)
{
    int n = blockIdx.x * blockDim.x + threadIdx.x;
    if (n >= N) return;
    float v[32];
    {
        float dn = den0[n];
        float inv = dn > 0.f ? 1.f / dn : 0.f;
        const float4* a0 = reinterpret_cast<const float4*>(acc0 + (size_t)n * 32);
#pragma unroll
        for (int i = 0; i < 8; ++i) {
            float4 t = a0[i];
            v[4 * i] = t.x * inv; v[4 * i + 1] = t.y * inv;
            v[4 * i + 2] = t.z * inv; v[4 * i + 3] = t.w * inv;
        }
    }
    if (acc1 != nullptr) {
        float dn = den1[n];
        float inv = dn > 0.f ? 1.f / dn : 0.f;
        const float4* a1 = reinterpret_cast<const float4*>(acc1 + (size_t)n * 32);
#pragma unroll
        for (int i = 0; i < 8; ++i) {
            float4 t = a1[i];
            v[4 * i] += t.x * inv; v[4 * i + 1] += t.y * inv;
            v[4 * i + 2] += t.z * inv; v[4 * i + 3] += t.w * inv;
        }
    }
#pragma unroll
    for (int h = 0; h < 32; ++h) {
        float t = scale * v[h] + bias[h];
        v[h] = t > 0.f ? t : 0.f;
    }
    float y[32];
#pragma unroll
    for (int j = 0; j < 32; ++j) y[j] = linb[j];
#pragma unroll
    for (int h = 0; h < 32; ++h) {
        float vh = v[h];
#pragma unroll
        for (int j = 0; j < 32; ++j) y[j] += vh * linW[h * 32 + j];
    }
    float4* o = reinterpret_cast<float4*>(out + (size_t)n * 32);
#pragma unroll
    for (int i = 0; i < 8; ++i)
        o[i] = make_float4(y[4 * i], y[4 * i + 1], y[4 * i + 2], y[4 * i + 3]);
}

extern "C" void kernel_launch(void* const* d_in, const int* in_sizes, int n_in,
                              void* d_out, int out_size, void* d_ws, size_t ws_size,
                              hipStream_t stream)
{
    const float* x_author = (const float*)d_in[0];
    const float* x_paper  = (const float*)d_in[1];
    const float* x_unit   = (const float*)d_in[2];
    const int* writes_src = (const int*)d_in[3];
    const int* writes_dst = (const int*)d_in[4];
    const int* pub_src    = (const int*)d_in[5];
    const int* pub_dst    = (const int*)d_in[6];
    const float* wr_Ws = (const float*)d_in[7];
    const float* wr_Wd = (const float*)d_in[8];
    const float* wr_as = (const float*)d_in[9];
    const float* wr_ad = (const float*)d_in[10];
    const float* wr_b  = (const float*)d_in[11];
    const float* pi_Ws = (const float*)d_in[12];
    const float* pi_Wd = (const float*)d_in[13];
    const float* pi_as = (const float*)d_in[14];
    const float* pi_ad = (const float*)d_in[15];
    const float* pi_b  = (const float*)d_in[16];
    const float* rw_Ws = (const float*)d_in[17];
    const float* rw_Wd = (const float*)d_in[18];
    const float* rw_as = (const float*)d_in[19];
    const float* rw_ad = (const float*)d_in[20];
    const float* rw_b  = (const float*)d_in[21];
    const float* rp_Ws = (const float*)d_in[22];
    const float* rp_Wd = (const float*)d_in[23];
    const float* rp_as = (const float*)d_in[24];
    const float* rp_ad = (const float*)d_in[25];
    const float* rp_b  = (const float*)d_in[26];
    const float* lin_W = (const float*)d_in[27];
    const float* lin_b = (const float*)d_in[28];
    float* out = (float*)d_out;
    float* ws = (float*)d_ws;

    // workspace layout (float offsets, padded to 64)
    size_t off = 0;
    auto A = [&](size_t nf) { size_t o = off; off += (nf + 63) & ~(size_t)63; return o; };
    size_t oWA   = A(128 * 33);
    size_t oWP   = A(128 * 66);
    size_t oWU   = A(64 * 33);
    size_t oBias = A(96);
    size_t oHsWr = A((size_t)cNA * 32);
    size_t oHsPi = A((size_t)cNP * 32);
    size_t oHsRw = A((size_t)cNP * 32);
    size_t oHsRp = A((size_t)cNU * 32);
    size_t oSwr  = A(cNA);
    size_t oSpi  = A(cNP);
    size_t oSrw  = A(cNP);
    size_t oSrp  = A(cNU);
    size_t oDwr  = A(cNP);
    size_t oDrp  = A(cNP);
    size_t oDpi  = A(cNU);
    size_t oDrw  = A(cNA);
    // bucket-path buffers (written each launch; no zeroing needed)
    size_t oAccWr = A((size_t)cNP * 32);
    size_t oDenWr = A(cNP);
    size_t oAccRw = A((size_t)cNA * 32);
    size_t oDenRw = A(cNA);
    size_t oStP8  = A((size_t)cNBP * 8);
    size_t oCurP8 = A((size_t)cNBP * 8);
    size_t oStA8  = A((size_t)cNBA * 8);
    size_t oCurA8 = A((size_t)cNBA * 8);
    size_t oBsP   = A(64);
    size_t oBsA   = A(64);
    size_t oBinW  = A(cEW);   // packed (author<<6 | paper&63), grouped by paper bucket
    size_t oBinR  = A(cEW);   // packed (paper<<5 | author&31), grouped by author bucket
    // zero-region: bucket histograms + atomic-path accumulators (pub relations)
    size_t zs = off;
    size_t oCntP8 = A((size_t)cNBP * 8);
    size_t oCntA8 = A((size_t)cNBA * 8);
    size_t oDenRp = A(cNP);
    size_t oDenPi = A(cNU);
    size_t oAccRp = A((size_t)cNP * 32);
    size_t oAccPi = A((size_t)cNU * 32);
    size_t ze = off;

    hipMemsetAsync((void*)(ws + zs), 0, (ze - zs) * sizeof(float), stream);

    prep_kernel<<<1, 128, 0, stream>>>(
        wr_Ws, wr_Wd, wr_ad, wr_b,
        pi_Ws, pi_Wd, pi_ad, pi_b,
        rw_Ws, rw_Wd, rw_ad, rw_b,
        rp_Ws, rp_Wd, rp_ad, rp_b,
        ws + oWA, ws + oWP, ws + oWU, ws + oBias);

    // ---- bucket-bin build for writes relation (both directions) ----
    {
        int* cntP8 = (int*)(ws + oCntP8);
        int* cntA8 = (int*)(ws + oCntA8);
        int* stP8  = (int*)(ws + oStP8);
        int* curP8 = (int*)(ws + oCurP8);
        int* stA8  = (int*)(ws + oStA8);
        int* curA8 = (int*)(ws + oCurA8);
        int* bsP   = (int*)(ws + oBsP);
        int* bsA   = (int*)(ws + oBsA);
        int* binW  = (int*)(ws + oBinW);
        int* binR  = (int*)(ws + oBinR);

        int eb = (cEW + 255) / 256;
        bhist_kernel<<<eb, 256, 0, stream>>>(writes_src, writes_dst, cntP8, cntA8, cEW);

        int nP8 = cNBP * 8, nA8 = cNBA * 8;
        int nbP = (nP8 + 2047) / 2048;
        int nbA = (nA8 + 2047) / 2048;
        scanA_kernel<<<nbP, 256, 0, stream>>>(cntP8, bsP, nP8);
        scanA_kernel<<<nbA, 256, 0, stream>>>(cntA8, bsA, nA8);
        scanB_kernel<<<1, 1, 0, stream>>>(bsP, nbP);
        scanB_kernel<<<1, 1, 0, stream>>>(bsA, nbA);
        scanC_kernel<<<nbP, 256, 0, stream>>>(cntP8, bsP, stP8, curP8, nP8);
        scanC_kernel<<<nbA, 256, 0, stream>>>(cntA8, bsA, stA8, curA8, nA8);

        bbin_kernel<<<eb, 256, 0, stream>>>(writes_src, writes_dst,
                                            curP8, curA8, binW, binR, cEW);
    }

    proj_kernel<128, 1, 1><<<(cNA + 255) / 256, 256, 0, stream>>>(
        x_author, ws + oWA, cNA, wr_as, nullptr,
        ws + oHsWr, ws + oSwr, nullptr, nullptr, ws + oDrw, nullptr);
    proj_kernel<128, 2, 2><<<(cNP + 255) / 256, 256, 0, stream>>>(
        x_paper, ws + oWP, cNP, pi_as, rw_as,
        ws + oHsPi, ws + oSpi, ws + oHsRw, ws + oSrw, ws + oDwr, ws + oDrp);
    proj_kernel<64, 1, 1><<<(cNU + 255) / 256, 256, 0, stream>>>(
        x_unit, ws + oWU, cNU, rp_as, nullptr,
        ws + oHsRp, ws + oSrp, nullptr, nullptr, ws + oDpi, nullptr);

    // ---- writes relation: LDS bucket accumulation ----
    // wr: author -> paper (buckets of 64 papers; src=author)
    bucket_acc_kernel<cPSH><<<cNBP, 256, 0, stream>>>(
        (int*)(ws + oBinW), (int*)(ws + oStP8),
        ws + oSwr, ws + oDwr, ws + oHsWr,
        ws + oAccWr, ws + oDenWr, cNP, cEW);
    // rw: paper -> author (buckets of 32 authors; src=paper)
    bucket_acc_kernel<cASH><<<cNBA, 256, 0, stream>>>(
        (int*)(ws + oBinR), (int*)(ws + oStA8),
        ws + oSrw, ws + oDrw, ws + oHsRw,
        ws + oAccRw, ws + oDenRw, cNA, cEW);

    // ---- pub relations: atomic path (small: 200K edges) ----
    {
        int blocks = (int)(((long long)cEP * 32 + 255) / 256);
        // pi: paper -> unit (acc region 640KB)
        edge_kernel<<<blocks, 256, 0, stream>>>(
            pub_src, pub_dst, ws + oSpi, ws + oDpi, ws + oHsPi,
            ws + oDenPi, ws + oAccPi, cEP);
        // rp: unit -> paper
        edge_kernel<<<blocks, 256, 0, stream>>>(
            pub_dst, pub_src, ws + oSrp, ws + oDrp, ws + oHsRp,
            ws + oDenRp, ws + oAccRp, cEP);
    }

    // outputs: author, paper, unit (concatenated)
    final_kernel<<<(cNA + 255) / 256, 256, 0, stream>>>(
        ws + oAccRw, ws + oDenRw, nullptr, nullptr,
        ws + oBias + 0, 1.0f, lin_W, lin_b, out, cNA);
    final_kernel<<<(cNP + 255) / 256, 256, 0, stream>>>(
        ws + oAccWr, ws + oDenWr, ws + oAccRp, ws + oDenRp,
        ws + oBias + 32, 0.5f, lin_W, lin_b, out + (size_t)cNA * 32, cNP);
    final_kernel<<<(cNU + 255) / 256, 256, 0, stream>>>(
        ws + oAccPi, ws + oDenPi, nullptr, nullptr,
        ws + oBias + 64, 1.0f, lin_W, lin_b, out + (size_t)(cNA + cNP) * 32, cNU);
}

// Round 4
// 932.604 us; speedup vs baseline: 1.6451x; 1.4835x over previous
//
#include <hip/hip_runtime.h>
#include <cstdint>
#include <cstddef>

// Problem constants (match reference)
static constexpr int cNA = 100000, cNP = 200000, cNU = 5000;
static constexpr int cDA = 128, cDP = 128, cDU = 64, cH = 32;
static constexpr int cEW = 2000000, cEP = 200000;

// ---------------------------------------------------------------------------
// prep: build combined per-node-type weight matrices and bias vectors.
//  W_A [128][33] : cols 0..31 = wr_Ws, col 32 = rw_Wd @ rw_ad
//  W_P [128][66] : cols 0..31 = pi_Ws, 32..63 = rw_Ws, 64 = wr_Wd@wr_ad, 65 = rp_Wd@rp_ad
//  W_U [ 64][33] : cols 0..31 = rp_Ws, col 32 = pi_Wd @ pi_ad
//  bias[0..31]=rw_b, bias[32..63]=0.5*(wr_b+rp_b), bias[64..95]=pi_b
// ---------------------------------------------------------------------------
__global__ void prep_kernel(
    const float* __restrict__ wr_Ws, const float* __restrict__ wr_Wd,
    const float* __restrict__ wr_ad, const float* __restrict__ wr_b,
    const float* __restrict__ pi_Ws, const float* __restrict__ pi_Wd,
    const float* __restrict__ pi_ad, const float* __restrict__ pi_b,
    const float* __restrict__ rw_Ws, const float* __restrict__ rw_Wd,
    const float* __restrict__ rw_ad, const float* __restrict__ rw_b,
    const float* __restrict__ rp_Ws, const float* __restrict__ rp_Wd,
    const float* __restrict__ rp_ad, const float* __restrict__ rp_b,
    float* __restrict__ W_A, float* __restrict__ W_P, float* __restrict__ W_U,
    float* __restrict__ bias)
{
    int k = threadIdx.x;  // 128 threads, 1 block
    if (k < 128) {
        for (int c = 0; c < 32; ++c) W_A[k * 33 + c] = wr_Ws[k * 32 + c];
        float dv = 0.f;
        for (int j = 0; j < 32; ++j) dv += rw_Wd[k * 32 + j] * rw_ad[j];
        W_A[k * 33 + 32] = dv;

        for (int c = 0; c < 32; ++c) W_P[k * 66 + c] = pi_Ws[k * 32 + c];
        for (int c = 0; c < 32; ++c) W_P[k * 66 + 32 + c] = rw_Ws[k * 32 + c];
        float d1 = 0.f, d2 = 0.f;
        for (int j = 0; j < 32; ++j) {
            d1 += wr_Wd[k * 32 + j] * wr_ad[j];
            d2 += rp_Wd[k * 32 + j] * rp_ad[j];
        }
        W_P[k * 66 + 64] = d1;
        W_P[k * 66 + 65] = d2;
    }
    if (k < 64) {
        for (int c = 0; c < 32; ++c) W_U[k * 33 + c] = rp_Ws[k * 32 + c];
        float dv = 0.f;
        for (int j = 0; j < 32; ++j) dv += pi_Wd[k * 32 + j] * pi_ad[j];
        W_U[k * 33 + 32] = dv;
    }
    if (k < 32) {
        bias[k]      = rw_b[k];
        bias[32 + k] = 0.5f * (wr_b[k] + rp_b[k]);
        bias[64 + k] = pi_b[k];
    }
}

// ---------------------------------------------------------------------------
// proj: per node type, one pass over x computing hs blocks (+ their s scalars)
// and d scalar columns, packed into float2 records per node so the edge
// kernel does ONE random 8B gather per node side instead of two 4B gathers.
//  NHS==1 (author/unit): p0[n] = SWAP ? (d0, s0) : (s0, d0)
//  NHS==2 (paper):       p0[n] = (d_wr, s_rw), p1[n] = (s_pi, d_rp)
// ---------------------------------------------------------------------------
template <int D, int NHS, bool SWAP>
__global__ __launch_bounds__(256) void proj_kernel(
    const float* __restrict__ x, const float* __restrict__ W, int N,
    const float* __restrict__ as0, const float* __restrict__ as1,
    float* __restrict__ hs0, float* __restrict__ hs1,
    float2* __restrict__ p0, float2* __restrict__ p1)
{
    constexpr int ND = (NHS == 2) ? 2 : 1;
    constexpr int C = NHS * 32 + ND;
    int n = blockIdx.x * blockDim.x + threadIdx.x;
    if (n >= N) return;
    float acc[C];
#pragma unroll
    for (int c = 0; c < C; ++c) acc[c] = 0.f;
    const float* xr = x + (size_t)n * D;
    for (int k = 0; k < D; k += 4) {
        float4 xv = *reinterpret_cast<const float4*>(xr + k);
        const float* w = W + (size_t)k * C;
#pragma unroll
        for (int c = 0; c < C; ++c) acc[c] += xv.x * w[c];
#pragma unroll
        for (int c = 0; c < C; ++c) acc[c] += xv.y * w[C + c];
#pragma unroll
        for (int c = 0; c < C; ++c) acc[c] += xv.z * w[2 * C + c];
#pragma unroll
        for (int c = 0; c < C; ++c) acc[c] += xv.w * w[3 * C + c];
    }
    float s0 = 0.f;
#pragma unroll
    for (int c = 0; c < 32; ++c) s0 += acc[c] * as0[c];
    {
        float4* o = reinterpret_cast<float4*>(hs0 + (size_t)n * 32);
#pragma unroll
        for (int i = 0; i < 8; ++i)
            o[i] = make_float4(acc[4 * i], acc[4 * i + 1], acc[4 * i + 2], acc[4 * i + 3]);
    }
    if constexpr (NHS == 2) {
        float s1 = 0.f;
#pragma unroll
        for (int c = 0; c < 32; ++c) s1 += acc[32 + c] * as1[c];
        float4* o = reinterpret_cast<float4*>(hs1 + (size_t)n * 32);
#pragma unroll
        for (int i = 0; i < 8; ++i)
            o[i] = make_float4(acc[32 + 4 * i], acc[32 + 4 * i + 1],
                               acc[32 + 4 * i + 2], acc[32 + 4 * i + 3]);
        p0[n] = make_float2(acc[64], s1);   // (d_wr, s_rw)
        p1[n] = make_float2(s0, acc[65]);   // (s_pi, d_rp)
    } else {
        float d0 = acc[32];
        p0[n] = SWAP ? make_float2(d0, s0) : make_float2(s0, d0);
    }
}

// ---------------------------------------------------------------------------
// edge2: both directions of one relation in a single pass. One 64-lane wave
// per edge: lanes 0..31 handle the forward direction (src->dst), lanes
// 32..63 the reverse (dst->src). Edge indices and the two packed float2
// scalar records are loaded once per edge (shared by both halves).
//   fwd: e = sp[si].x + dp[di].x ; acc = accF[di] += ex * hsF[si]
//   rev: e = dp[di].y + sp[si].y ; acc = accR[si] += ex * hsR[di]
// Softmax max-shift is skipped (|e| <= ~2 here); normalization deferred to
// final_kernel (acc/den), mathematically identical.
// ---------------------------------------------------------------------------
__global__ __launch_bounds__(256) void edge2_kernel(
    const int* __restrict__ src, const int* __restrict__ dst,
    const float2* __restrict__ sp, const float2* __restrict__ dp,
    const float* __restrict__ hsF, const float* __restrict__ hsR,
    float* __restrict__ accF, float* __restrict__ denF,
    float* __restrict__ accR, float* __restrict__ denR, int E)
{
    int g = blockIdx.x * 256 + threadIdx.x;
    int e = g >> 6;
    if (e >= E) return;
    int h = g & 63;
    int si = src[e], di = dst[e];
    float2 a = sp[si];
    float2 p = dp[di];
    bool fwd = (h < 32);
    int l = h & 31;
    float ev = fwd ? (a.x + p.x) : (p.y + a.y);
    ev = ev >= 0.f ? ev : 0.2f * ev;
    float ex = __expf(ev);
    const float* ht = fwd ? hsF : hsR;
    int gn = fwd ? si : di;
    float hv = ht[(size_t)gn * 32 + l];
    float* at = fwd ? accF : accR;
    int an = fwd ? di : si;
    atomicAdd(at + (size_t)an * 32 + l, ex * hv);
    if (l == 0) atomicAdd((fwd ? denF : denR) + an, ex);
}

// ---------------------------------------------------------------------------
// final: combine relations, /den (0 if no in-edges), +bias, relu, @lin_W+lin_b
// ---------------------------------------------------------------------------
__global__ __launch_bounds__(256) void final_kernel(
    const float* __restrict__ acc0, const float* __restrict__ den0,
    const float* __restrict__ acc1, const float* __restrict__ den1,
    const float* __restrict__ bias, float scale,
    const float* __restrict__ linW, const float* __restrict__ linb,
    float* __restrict__ out, int N)
{
    int n = blockIdx.x * blockDim.x + threadIdx.x;
    if (n >= N) return;
    float v[32];
    {
        float dn = den0[n];
        float inv = dn > 0.f ? 1.f / dn : 0.f;
        const float4* a0 = reinterpret_cast<const float4*>(acc0 + (size_t)n * 32);
#pragma unroll
        for (int i = 0; i < 8; ++i) {
            float4 t = a0[i];
            v[4 * i] = t.x * inv; v[4 * i + 1] = t.y * inv;
            v[4 * i + 2] = t.z * inv; v[4 * i + 3] = t.w * inv;
        }
    }
    if (acc1 != nullptr) {
        float dn = den1[n];
        float inv = dn > 0.f ? 1.f / dn : 0.f;
        const float4* a1 = reinterpret_cast<const float4*>(acc1 + (size_t)n * 32);
#pragma unroll
        for (int i = 0; i < 8; ++i) {
            float4 t = a1[i];
            v[4 * i] += t.x * inv; v[4 * i + 1] += t.y * inv;
            v[4 * i + 2] += t.z * inv; v[4 * i + 3] += t.w * inv;
        }
    }
#pragma unroll
    for (int h = 0; h < 32; ++h) {
        float t = scale * v[h] + bias[h];
        v[h] = t > 0.f ? t : 0.f;
    }
    float y[32];
#pragma unroll
    for (int j = 0; j < 32; ++j) y[j] = linb[j];
#pragma unroll
    for (int h = 0; h < 32; ++h) {
        float vh = v[h];
#pragma unroll
        for (int j = 0; j < 32; ++j) y[j] += vh * linW[h * 32 + j];
    }
    float4* o = reinterpret_cast<float4*>(out + (size_t)n * 32);
#pragma unroll
    for (int i = 0; i < 8; ++i)
        o[i] = make_float4(y[4 * i], y[4 * i + 1], y[4 * i + 2], y[4 * i + 3]);
}

extern "C" void kernel_launch(void* const* d_in, const int* in_sizes, int n_in,
                              void* d_out, int out_size, void* d_ws, size_t ws_size,
                              hipStream_t stream)
{
    const float* x_author = (const float*)d_in[0];
    const float* x_paper  = (const float*)d_in[1];
    const float* x_unit   = (const float*)d_in[2];
    const int* writes_src = (const int*)d_in[3];
    const int* writes_dst = (const int*)d_in[4];
    const int* pub_src    = (const int*)d_in[5];
    const int* pub_dst    = (const int*)d_in[6];
    const float* wr_Ws = (const float*)d_in[7];
    const float* wr_Wd = (const float*)d_in[8];
    const float* wr_as = (const float*)d_in[9];
    const float* wr_ad = (const float*)d_in[10];
    const float* wr_b  = (const float*)d_in[11];
    const float* pi_Ws = (const float*)d_in[12];
    const float* pi_Wd = (const float*)d_in[13];
    const float* pi_as = (const float*)d_in[14];
    const float* pi_ad = (const float*)d_in[15];
    const float* pi_b  = (const float*)d_in[16];
    const float* rw_Ws = (const float*)d_in[17];
    const float* rw_Wd = (const float*)d_in[18];
    const float* rw_as = (const float*)d_in[19];
    const float* rw_ad = (const float*)d_in[20];
    const float* rw_b  = (const float*)d_in[21];
    const float* rp_Ws = (const float*)d_in[22];
    const float* rp_Wd = (const float*)d_in[23];
    const float* rp_as = (const float*)d_in[24];
    const float* rp_ad = (const float*)d_in[25];
    const float* rp_b  = (const float*)d_in[26];
    const float* lin_W = (const float*)d_in[27];
    const float* lin_b = (const float*)d_in[28];
    float* out = (float*)d_out;
    float* ws = (float*)d_ws;

    // workspace layout (float offsets, padded to 64)
    size_t off = 0;
    auto A = [&](size_t nf) { size_t o = off; off += (nf + 63) & ~(size_t)63; return o; };
    size_t oWA   = A(128 * 33);
    size_t oWP   = A(128 * 66);
    size_t oWU   = A(64 * 33);
    size_t oBias = A(96);
    size_t oHsWr = A((size_t)cNA * 32);
    size_t oHsPi = A((size_t)cNP * 32);
    size_t oHsRw = A((size_t)cNP * 32);
    size_t oHsRp = A((size_t)cNU * 32);
    size_t oPA   = A((size_t)cNA * 2);   // (s_wr, d_rw) per author
    size_t oPPw  = A((size_t)cNP * 2);   // (d_wr, s_rw) per paper
    size_t oPPp  = A((size_t)cNP * 2);   // (s_pi, d_rp) per paper
    size_t oPU   = A((size_t)cNU * 2);   // (d_pi, s_rp) per unit
    // zero-region: all atomic accumulators
    size_t zs = off;
    size_t oDenWr = A(cNP);
    size_t oDenRw = A(cNA);
    size_t oDenPi = A(cNU);
    size_t oDenRp = A(cNP);
    size_t oAccWr = A((size_t)cNP * 32);
    size_t oAccRw = A((size_t)cNA * 32);
    size_t oAccPi = A((size_t)cNU * 32);
    size_t oAccRp = A((size_t)cNP * 32);
    size_t ze = off;

    hipMemsetAsync((void*)(ws + zs), 0, (ze - zs) * sizeof(float), stream);

    prep_kernel<<<1, 128, 0, stream>>>(
        wr_Ws, wr_Wd, wr_ad, wr_b,
        pi_Ws, pi_Wd, pi_ad, pi_b,
        rw_Ws, rw_Wd, rw_ad, rw_b,
        rp_Ws, rp_Wd, rp_ad, rp_b,
        ws + oWA, ws + oWP, ws + oWU, ws + oBias);

    // ---- projections (hs tables + packed per-node scalar records) ----
    proj_kernel<128, 1, false><<<(cNA + 255) / 256, 256, 0, stream>>>(
        x_author, ws + oWA, cNA, wr_as, nullptr,
        ws + oHsWr, nullptr, (float2*)(ws + oPA), nullptr);
    proj_kernel<128, 2, false><<<(cNP + 255) / 256, 256, 0, stream>>>(
        x_paper, ws + oWP, cNP, pi_as, rw_as,
        ws + oHsPi, ws + oHsRw, (float2*)(ws + oPPw), (float2*)(ws + oPPp));
    proj_kernel<64, 1, true><<<(cNU + 255) / 256, 256, 0, stream>>>(
        x_unit, ws + oWU, cNU, rp_as, nullptr,
        ws + oHsRp, nullptr, (float2*)(ws + oPU), nullptr);

    // ---- writes relation: both directions in one pass ----
    {
        int blocks = (int)(((long long)cEW * 64 + 255) / 256);
        edge2_kernel<<<blocks, 256, 0, stream>>>(
            writes_src, writes_dst,
            (const float2*)(ws + oPA), (const float2*)(ws + oPPw),
            ws + oHsWr, ws + oHsRw,
            ws + oAccWr, ws + oDenWr, ws + oAccRw, ws + oDenRw, cEW);
    }
    // ---- pub relation: both directions in one pass ----
    {
        int blocks = (int)(((long long)cEP * 64 + 255) / 256);
        edge2_kernel<<<blocks, 256, 0, stream>>>(
            pub_src, pub_dst,
            (const float2*)(ws + oPPp), (const float2*)(ws + oPU),
            ws + oHsPi, ws + oHsRp,
            ws + oAccPi, ws + oDenPi, ws + oAccRp, ws + oDenRp, cEP);
    }

    // outputs: author, paper, unit (concatenated)
    final_kernel<<<(cNA + 255) / 256, 256, 0, stream>>>(
        ws + oAccRw, ws + oDenRw, nullptr, nullptr,
        ws + oBias + 0, 1.0f, lin_W, lin_b, out, cNA);
    final_kernel<<<(cNP + 255) / 256, 256, 0, stream>>>(
        ws + oAccWr, ws + oDenWr, ws + oAccRp, ws + oDenRp,
        ws + oBias + 32, 0.5f, lin_W, lin_b, out + (size_t)cNA * 32, cNP);
    final_kernel<<<(cNU + 255) / 256, 256, 0, stream>>>(
        ws + oAccPi, ws + oDenPi, nullptr, nullptr,
        ws + oBias + 64, 1.0f, lin_W, lin_b, out + (size_t)(cNA + cNP) * 32, cNU);
}